// Round 1
// baseline (2154.834 us; speedup 1.0000x reference)
//
#include <hip/hip_runtime.h>
#include <hip/hip_bf16.h>
#include <stdint.h>

#define N_NODES 100000
#define N_EDGES 1600000
#define D_FEAT 32
#define CUT_K 320000   // int(N_EDGES * 0.2)

struct SelState { unsigned long long prefix; unsigned int k; };

__global__ void deg_kernel(const int* __restrict__ dst, int* __restrict__ deg, int E) {
    int e = blockIdx.x * blockDim.x + threadIdx.x;
    if (e < E) atomicAdd(&deg[dst[e]], 1);
}

__global__ void norm_kernel(const int* __restrict__ deg, float* __restrict__ nrm, int N) {
    int i = blockIdx.x * blockDim.x + threadIdx.x;
    if (i < N) nrm[i] = 1.0f / sqrtf(fmaxf((float)deg[i], 1.0f));
}

// nh = h / max(||h||_2, 1e-12), one thread per node, float4 vectorized
__global__ void rownorm_kernel(const float* __restrict__ h, float* __restrict__ nh, int N) {
    int i = blockIdx.x * blockDim.x + threadIdx.x;
    if (i >= N) return;
    const float4* hp = (const float4*)(h + (size_t)i * D_FEAT);
    float4 v[8];
    float ss = 0.f;
#pragma unroll
    for (int q = 0; q < 8; ++q) {
        v[q] = hp[q];
        ss += v[q].x * v[q].x + v[q].y * v[q].y + v[q].z * v[q].z + v[q].w * v[q].w;
    }
    float inv = 1.0f / fmaxf(sqrtf(ss), 1e-12f);
    float4* op = (float4*)(nh + (size_t)i * D_FEAT);
#pragma unroll
    for (int q = 0; q < 8; ++q) {
        float4 ov = v[q];
        ov.x *= inv; ov.y *= inv; ov.z *= inv; ov.w *= inv;
        op[q] = ov;
    }
}

// keys[e] = (sortable(cos_e) << 32) | e   -- all keys distinct, matches top_k tie-break
__global__ void coskey_kernel(const float* __restrict__ nh, const int* __restrict__ src,
                              const int* __restrict__ dst,
                              unsigned long long* __restrict__ keys, int E) {
    int e = blockIdx.x * blockDim.x + threadIdx.x;
    if (e >= E) return;
    const float4* a = (const float4*)(nh + (size_t)src[e] * D_FEAT);
    const float4* b = (const float4*)(nh + (size_t)dst[e] * D_FEAT);
    float s = 0.f;
#pragma unroll
    for (int q = 0; q < 8; ++q) {
        float4 x = a[q], y = b[q];
        s += x.x * y.x + x.y * y.y + x.z * y.z + x.w * y.w;
    }
    unsigned int u = __float_as_uint(s);
    unsigned int so = (u & 0x80000000u) ? ~u : (u | 0x80000000u);
    keys[e] = ((unsigned long long)so << 32) | (unsigned int)e;
}

__global__ void initsel_kernel(SelState* st) { st->prefix = 0ull; st->k = CUT_K; }

// radix-select histogram pass: 16-bit digit, MSB first
__global__ void hist_kernel(const unsigned long long* __restrict__ keys, int E,
                            unsigned int* __restrict__ hist,
                            const SelState* __restrict__ st, int pass) {
    unsigned long long prefix = st->prefix;
    int dshift = 48 - 16 * pass;
    int stride = gridDim.x * blockDim.x;
    for (int e = blockIdx.x * blockDim.x + threadIdx.x; e < E; e += stride) {
        unsigned long long key = keys[e];
        bool ok = true;
        if (pass > 0) ok = ((key >> (64 - 16 * pass)) == prefix);
        if (ok) atomicAdd(&hist[(unsigned int)((key >> dshift) & 0xFFFFull)], 1u);
    }
}

// single block: scan 65536 bins, pick digit containing rank k, update state, zero hist
__global__ void scan_kernel(unsigned int* __restrict__ hist, SelState* __restrict__ st) {
    __shared__ unsigned int buf[1024];
    int t = threadIdx.x;
    unsigned int k = st->k;           // all threads read BEFORE any write (syncs below separate)
    int base = t * 64;
    unsigned int s = 0;
    for (int i = 0; i < 64; ++i) s += hist[base + i];
    buf[t] = s;
    __syncthreads();
    for (int off = 1; off < 1024; off <<= 1) {
        unsigned int v = (t >= off) ? buf[t - off] : 0u;
        __syncthreads();
        buf[t] += v;
        __syncthreads();
    }
    unsigned int incl = buf[t];
    unsigned int excl = incl - s;
    if (excl < k && k <= incl) {      // exactly one thread wins
        unsigned int run = excl;
        for (int i = 0; i < 64; ++i) {
            unsigned int c = hist[base + i];
            if (run < k && k <= run + c) {
                st->prefix = (st->prefix << 16) | (unsigned long long)(base + i);
                st->k = k - run;
                break;
            }
            run += c;
        }
    }
    __syncthreads();
    for (int i = 0; i < 64; ++i) hist[base + i] = 0u;   // ready for next pass
}

// per edge: if kept, h_out[dst] += h_in[src] * nrm[src] * nrm[dst] (32 lanes = 32 dims)
__global__ void aggregate_kernel(const float* __restrict__ h_in, float* __restrict__ h_out,
                                 const int* __restrict__ src, const int* __restrict__ dst,
                                 const float* __restrict__ nrm,
                                 const unsigned long long* __restrict__ keys,
                                 const SelState* __restrict__ st, int E) {
    unsigned long long kth = st->prefix;   // cut_k-th smallest composite key
    long long idx = (long long)blockIdx.x * blockDim.x + threadIdx.x;
    int e = (int)(idx >> 5);
    int j = (int)(idx & 31);
    if (e >= E) return;
    if (keys[e] <= kth) return;            // pruned (exactly CUT_K edges)
    int s = src[e], d = dst[e];
    float val = h_in[(size_t)s * D_FEAT + j] * nrm[s] * nrm[d];
    atomicAdd(&h_out[(size_t)d * D_FEAT + j], val);
}

// out = h @ W^T ; W is [32,32] row-major; stage W transposed in LDS (pad 33, conflict-free)
__global__ void fc_kernel(const float* __restrict__ h, const float* __restrict__ W,
                          float* __restrict__ out, int N) {
    __shared__ float Wt[32][33];
    int t = threadIdx.x;
    for (int i = t; i < 1024; i += 256) Wt[i & 31][i >> 5] = W[i];
    __syncthreads();
    int node = blockIdx.x * 8 + (t >> 5);
    if (node >= N) return;
    int o = t & 31;
    const float* hr = h + (size_t)node * D_FEAT;
    float acc = 0.f;
#pragma unroll
    for (int j = 0; j < 32; ++j) acc += hr[j] * Wt[j][o];
    out[(size_t)node * D_FEAT + o] = acc;
}

extern "C" void kernel_launch(void* const* d_in, const int* in_sizes, int n_in,
                              void* d_out, int out_size, void* d_ws, size_t ws_size,
                              hipStream_t stream) {
    const float* features = (const float*)d_in[0];
    const float* W        = (const float*)d_in[1];
    const int*   src      = (const int*)d_in[2];
    const int*   dst      = (const int*)d_in[3];
    float*       out      = (float*)d_out;

    char* ws = (char*)d_ws;
    size_t o = 0;
    auto take = [&](size_t bytes) -> char* {
        char* p = ws + o;
        o += (bytes + 255) & ~(size_t)255;
        return p;
    };
    int*                deg  = (int*)take((size_t)N_NODES * 4);
    float*              nrm  = (float*)take((size_t)N_NODES * 4);
    float*              hA   = (float*)take((size_t)N_NODES * D_FEAT * 4);
    float*              hB   = (float*)take((size_t)N_NODES * D_FEAT * 4);
    float*              nh   = (float*)take((size_t)N_NODES * D_FEAT * 4);
    unsigned long long* keys = (unsigned long long*)take((size_t)N_EDGES * 8);
    unsigned int*       hist = (unsigned int*)take((size_t)65536 * 4);
    SelState*           st   = (SelState*)take(256);

    hipMemsetAsync(deg, 0, (size_t)N_NODES * 4, stream);
    hipMemsetAsync(hist, 0, (size_t)65536 * 4, stream);

    deg_kernel<<<(N_EDGES + 255) / 256, 256, 0, stream>>>(dst, deg, N_EDGES);
    norm_kernel<<<(N_NODES + 255) / 256, 256, 0, stream>>>(deg, nrm, N_NODES);

    const float* hin = features;
    float* houts[2] = { hA, hB };
    for (int hop = 0; hop < 2; ++hop) {
        float* hout = houts[hop];
        rownorm_kernel<<<(N_NODES + 255) / 256, 256, 0, stream>>>(hin, nh, N_NODES);
        coskey_kernel<<<(N_EDGES + 255) / 256, 256, 0, stream>>>(nh, src, dst, keys, N_EDGES);
        initsel_kernel<<<1, 1, 0, stream>>>(st);
        for (int pass = 0; pass < 4; ++pass) {
            hist_kernel<<<1024, 256, 0, stream>>>(keys, N_EDGES, hist, st, pass);
            scan_kernel<<<1, 1024, 0, stream>>>(hist, st);
        }
        hipMemsetAsync(hout, 0, (size_t)N_NODES * D_FEAT * 4, stream);
        long long agg_threads = (long long)N_EDGES * 32;
        aggregate_kernel<<<(int)((agg_threads + 255) / 256), 256, 0, stream>>>(
            hin, hout, src, dst, nrm, keys, st, N_EDGES);
        hin = hout;
    }
    fc_kernel<<<(N_NODES + 7) / 8, 256, 0, stream>>>(hin, W, out, N_NODES);
}

// Round 2
// 1189.487 us; speedup vs baseline: 1.8116x; 1.8116x over previous
//
#include <hip/hip_runtime.h>
#include <hip/hip_bf16.h>
#include <stdint.h>

#define N_NODES 100000
#define N_EDGES 1600000
#define D_FEAT 32
#define CUT_K 320000   // int(N_EDGES * 0.2)
#define HIST_NB 1024   // blocks in hist pass; slices buffer = HIST_NB*256 u32

struct SelState { unsigned long long prefix; unsigned int k; };

__global__ void deg_kernel(const int* __restrict__ dst, int* __restrict__ deg, int E) {
    int e = blockIdx.x * blockDim.x + threadIdx.x;
    if (e < E) atomicAdd(&deg[dst[e]], 1);
}

__global__ void norm_kernel(const int* __restrict__ deg, float* __restrict__ nrm, int N) {
    int i = blockIdx.x * blockDim.x + threadIdx.x;
    if (i < N) nrm[i] = 1.0f / sqrtf(fmaxf((float)deg[i], 1.0f));
}

// nh = h / max(||h||_2, 1e-12), one thread per node, float4 vectorized
__global__ void rownorm_kernel(const float* __restrict__ h, float* __restrict__ nh, int N) {
    int i = blockIdx.x * blockDim.x + threadIdx.x;
    if (i >= N) return;
    const float4* hp = (const float4*)(h + (size_t)i * D_FEAT);
    float4 v[8];
    float ss = 0.f;
#pragma unroll
    for (int q = 0; q < 8; ++q) {
        v[q] = hp[q];
        ss += v[q].x * v[q].x + v[q].y * v[q].y + v[q].z * v[q].z + v[q].w * v[q].w;
    }
    float inv = 1.0f / fmaxf(sqrtf(ss), 1e-12f);
    float4* op = (float4*)(nh + (size_t)i * D_FEAT);
#pragma unroll
    for (int q = 0; q < 8; ++q) {
        float4 ov = v[q];
        ov.x *= inv; ov.y *= inv; ov.z *= inv; ov.w *= inv;
        op[q] = ov;
    }
}

// keys[e] = (sortable(cos_e) << 32) | e   -- all keys distinct, matches top_k tie-break
__global__ void coskey_kernel(const float* __restrict__ nh, const int* __restrict__ src,
                              const int* __restrict__ dst,
                              unsigned long long* __restrict__ keys, int E) {
    int e = blockIdx.x * blockDim.x + threadIdx.x;
    if (e >= E) return;
    const float4* a = (const float4*)(nh + (size_t)src[e] * D_FEAT);
    const float4* b = (const float4*)(nh + (size_t)dst[e] * D_FEAT);
    float s = 0.f;
#pragma unroll
    for (int q = 0; q < 8; ++q) {
        float4 x = a[q], y = b[q];
        s += x.x * y.x + x.y * y.y + x.z * y.z + x.w * y.w;
    }
    unsigned int u = __float_as_uint(s);
    unsigned int so = (u & 0x80000000u) ? ~u : (u | 0x80000000u);
    keys[e] = ((unsigned long long)so << 32) | (unsigned int)e;
}

__global__ void initsel_kernel(SelState* st) { st->prefix = 0ull; st->k = CUT_K; }

// radix-select histogram pass: 8-bit digit, MSB first, per-wave LDS hists,
// per-block non-atomic slice writes (no global atomics at all)
__global__ void hist8_kernel(const unsigned long long* __restrict__ keys, int E,
                             unsigned int* __restrict__ slices,
                             const SelState* __restrict__ st, int pass) {
    __shared__ unsigned int lh[4][256];
    int t = threadIdx.x;
#pragma unroll
    for (int w = 0; w < 4; ++w) lh[w][t] = 0u;
    __syncthreads();
    unsigned long long prefix = st->prefix;
    int wave = t >> 6;
    int dshift = 56 - 8 * pass;
    int pshift = 64 - 8 * pass;   // valid only when pass>0
    int stride = gridDim.x * blockDim.x;
    for (int e = blockIdx.x * blockDim.x + t; e < E; e += stride) {
        unsigned long long key = keys[e];
        bool ok = (pass == 0) || ((key >> pshift) == prefix);
        if (ok) atomicAdd(&lh[wave][(unsigned int)((key >> dshift) & 0xFFull)], 1u);
    }
    __syncthreads();
    slices[(size_t)blockIdx.x * 256 + t] = lh[0][t] + lh[1][t] + lh[2][t] + lh[3][t];
}

// single block of 256 threads: reduce slices, scan 256 bins, pick digit at rank k
__global__ void scan8_kernel(const unsigned int* __restrict__ slices,
                             SelState* __restrict__ st) {
    __shared__ unsigned int buf[256];
    int t = threadIdx.x;
    unsigned int k = st->k;            // read before any write
    unsigned int s = 0;
#pragma unroll 8
    for (int b = 0; b < HIST_NB; ++b) s += slices[(size_t)b * 256 + t];
    buf[t] = s;
    __syncthreads();
    for (int off = 1; off < 256; off <<= 1) {
        unsigned int v = (t >= off) ? buf[t - off] : 0u;
        __syncthreads();
        buf[t] += v;
        __syncthreads();
    }
    unsigned int incl = buf[t];
    unsigned int excl = incl - s;
    if (excl < k && k <= incl) {       // exactly one thread wins
        st->prefix = (st->prefix << 8) | (unsigned long long)t;
        st->k = k - excl;
    }
}

// per edge: if kept, h_out[dst] += h_in[src] * nrm[src] * nrm[dst] (32 lanes = 32 dims)
__global__ void aggregate_kernel(const float* __restrict__ h_in, float* __restrict__ h_out,
                                 const int* __restrict__ src, const int* __restrict__ dst,
                                 const float* __restrict__ nrm,
                                 const unsigned long long* __restrict__ keys,
                                 const SelState* __restrict__ st, int E) {
    unsigned long long kth = st->prefix;   // cut_k-th smallest composite key
    long long idx = (long long)blockIdx.x * blockDim.x + threadIdx.x;
    int e = (int)(idx >> 5);
    int j = (int)(idx & 31);
    if (e >= E) return;
    if (keys[e] <= kth) return;            // pruned (exactly CUT_K edges)
    int s = src[e], d = dst[e];
    float val = h_in[(size_t)s * D_FEAT + j] * nrm[s] * nrm[d];
    atomicAdd(&h_out[(size_t)d * D_FEAT + j], val);
}

// out = h @ W^T ; W is [32,32] row-major; stage W transposed in LDS (pad 33, conflict-free)
__global__ void fc_kernel(const float* __restrict__ h, const float* __restrict__ W,
                          float* __restrict__ out, int N) {
    __shared__ float Wt[32][33];
    int t = threadIdx.x;
    for (int i = t; i < 1024; i += 256) Wt[i & 31][i >> 5] = W[i];
    __syncthreads();
    int node = blockIdx.x * 8 + (t >> 5);
    if (node >= N) return;
    int o = t & 31;
    const float* hr = h + (size_t)node * D_FEAT;
    float acc = 0.f;
#pragma unroll
    for (int j = 0; j < 32; ++j) acc += hr[j] * Wt[j][o];
    out[(size_t)node * D_FEAT + o] = acc;
}

extern "C" void kernel_launch(void* const* d_in, const int* in_sizes, int n_in,
                              void* d_out, int out_size, void* d_ws, size_t ws_size,
                              hipStream_t stream) {
    const float* features = (const float*)d_in[0];
    const float* W        = (const float*)d_in[1];
    const int*   src      = (const int*)d_in[2];
    const int*   dst      = (const int*)d_in[3];
    float*       out      = (float*)d_out;

    char* ws = (char*)d_ws;
    size_t o = 0;
    auto take = [&](size_t bytes) -> char* {
        char* p = ws + o;
        o += (bytes + 255) & ~(size_t)255;
        return p;
    };
    int*                deg    = (int*)take((size_t)N_NODES * 4);
    float*              nrm    = (float*)take((size_t)N_NODES * 4);
    float*              hA     = (float*)take((size_t)N_NODES * D_FEAT * 4);
    float*              hB     = (float*)take((size_t)N_NODES * D_FEAT * 4);
    float*              nh     = (float*)take((size_t)N_NODES * D_FEAT * 4);
    unsigned long long* keys   = (unsigned long long*)take((size_t)N_EDGES * 8);
    unsigned int*       slices = (unsigned int*)take((size_t)HIST_NB * 256 * 4);
    SelState*           st     = (SelState*)take(256);

    hipMemsetAsync(deg, 0, (size_t)N_NODES * 4, stream);

    deg_kernel<<<(N_EDGES + 255) / 256, 256, 0, stream>>>(dst, deg, N_EDGES);
    norm_kernel<<<(N_NODES + 255) / 256, 256, 0, stream>>>(deg, nrm, N_NODES);

    const float* hin = features;
    float* houts[2] = { hA, hB };
    for (int hop = 0; hop < 2; ++hop) {
        float* hout = houts[hop];
        rownorm_kernel<<<(N_NODES + 255) / 256, 256, 0, stream>>>(hin, nh, N_NODES);
        coskey_kernel<<<(N_EDGES + 255) / 256, 256, 0, stream>>>(nh, src, dst, keys, N_EDGES);
        initsel_kernel<<<1, 1, 0, stream>>>(st);
        for (int pass = 0; pass < 8; ++pass) {
            hist8_kernel<<<HIST_NB, 256, 0, stream>>>(keys, N_EDGES, slices, st, pass);
            scan8_kernel<<<1, 256, 0, stream>>>(slices, st);
        }
        hipMemsetAsync(hout, 0, (size_t)N_NODES * D_FEAT * 4, stream);
        long long agg_threads = (long long)N_EDGES * 32;
        aggregate_kernel<<<(int)((agg_threads + 255) / 256), 256, 0, stream>>>(
            hin, hout, src, dst, nrm, keys, st, N_EDGES);
        hin = hout;
    }
    fc_kernel<<<(N_NODES + 7) / 8, 256, 0, stream>>>(hin, W, out, N_NODES);
}